// Round 6
// baseline (162.591 us; speedup 1.0000x reference)
//
#include <hip/hip_runtime.h>

typedef _Float16 half_t;
typedef __attribute__((ext_vector_type(8))) _Float16 half8;   // MFMA A/B frag (4 VGPRs)
typedef __attribute__((ext_vector_type(4))) float f32x4;      // MFMA C/D frag

#define NPOLY 16384   // B*N
#define PPTS  32
#define CIN   9
#define FG_S  68      // fg row stride (halves): write banks 2-way max (free, m136)
#define FT_S  72      // ft/qt row stride

__device__ __forceinline__ half8 ld8(const half_t* p){
    return *reinterpret_cast<const half8*>(p);
}
__device__ __forceinline__ half8 h8z(){
    half8 v;
    #pragma unroll
    for (int j = 0; j < 8; j++) v[j] = (half_t)0.f;
    return v;
}
__device__ __forceinline__ f32x4 MFMA(half8 a, half8 b, f32x4 c){
    return __builtin_amdgcn_mfma_f32_16x16x32_f16(a, b, c, 0, 0, 0);
}
// Fragment layouts (measured, learn_hip m89/m120; dtype-independent):
//   A[m][k]: m = lane&15 (+16*mt), k = (lane>>4)*8 + j (+32*ks)
//   B[k][n]: n = lane&15 (+16*nt), k = (lane>>4)*8 + j (+32*ks)
//   C/D[row][col]: col = lane&15 (+16*nt), row = (lane>>4)*4 + r (+16*mt)

// =====================================================================
// Fully fused PointNet polyline encoder.
// Block = 512 threads (8 waves) = 32 polylines; wave w owns rows 4w..4w+3.
// Grid = 512 blocks = exactly 2 blocks/CU (no tail). LDS ~69.8 KB -> 2/CU.
// __launch_bounds__(512,2): min-waves=4 made the allocator clamp to 64
// VGPRs and spill ~25 regs (R4/R5: WRITE_SIZE 155/34.8 MB vs 8.4 ideal);
// with 2 the allocator is free (~92 regs < 128) and LDS alone pins
// occupancy at 2 blocks/CU.
// =====================================================================
__global__ __launch_bounds__(512, 2) void k_fused(
    const float* __restrict__ px,        // [NPOLY][32][9]
    const int*   __restrict__ pmask,     // [NPOLY][32]
    const float* __restrict__ w_pre, const float* __restrict__ b_pre,
    const float* __restrict__ g_pre, const float* __restrict__ be_pre,
    const float* __restrict__ rm_pre, const float* __restrict__ rv_pre,
    const float* __restrict__ w_m1, const float* __restrict__ b_m1,
    const float* __restrict__ g_m1, const float* __restrict__ be_m1,
    const float* __restrict__ rm_m1, const float* __restrict__ rv_m1,
    const float* __restrict__ w_m2, const float* __restrict__ b_m2,
    const float* __restrict__ g_m2, const float* __restrict__ be_m2,
    const float* __restrict__ rm_m2, const float* __restrict__ rv_m2,
    const float* __restrict__ w1, const float* __restrict__ b1,
    const float* __restrict__ w2, const float* __restrict__ b2,
    float* __restrict__ out)
{
    __shared__ __align__(16) half_t lds_w[24 * 512];     // 24 KB: m1 frags 0..15, m2 frags 16..23
    __shared__ __align__(16) half_t fg[8][32 * FG_S];    // 34 KB per-wave f/g A-tiles
    __shared__ __align__(16) half_t pooledb[8][64];      // 1 KB
    __shared__ __align__(16) half_t ft[32 * FT_S];       // 4.5 KB feat A-tile (32 rows)
    __shared__ __align__(16) half_t qt[32 * FT_S];       // 4.5 KB out1 A-tile
    __shared__ int validb[32];

    const int tid  = threadIdx.x;
    const int wave = tid >> 6, lane = tid & 63, l15 = lane & 15, q = lane >> 4;

    // ---- stage m1 (frags 0..15) + m2 (frags 16..23) into LDS, BN-scaled ----
    for (int s = tid; s < 24 * 64; s += 512) {
        int frag = s >> 6, ln = s & 63;
        const float *W, *G, *RV; int ks, nt;
        if (frag < 16) { W = w_m1; G = g_m1; RV = rv_m1; ks = frag >> 2; nt = frag & 3; }
        else           { W = w_m2; G = g_m2; RV = rv_m2; int f = frag - 16; ks = f >> 2; nt = f & 3; }
        int col = nt * 16 + (ln & 15);
        int kb  = ks * 32 + ((ln >> 4) << 3);
        float sA = G[col] * rsqrtf(RV[col] + 1e-5f);
        half_t* dst = &lds_w[s * 8];
        #pragma unroll
        for (int j = 0; j < 8; j++)
            dst[j] = (half_t)(W[(kb + j) * 64 + col] * sA);
    }

    // ---- pre-layer B-frags in registers (BN scale folded, bias at k=9) ----
    half8 bwp[4];
    float sC1c[4], sC2c[4];
    #pragma unroll
    for (int nt = 0; nt < 4; nt++) {
        int col = nt * 16 + l15;
        float a0 = g_pre[col] * rsqrtf(rv_pre[col] + 1e-5f);
        float c0 = (b_pre[col] - rm_pre[col]) * a0 + be_pre[col];
        half8 v = h8z();
        if (q == 0) {
            #pragma unroll
            for (int j = 0; j < 8; j++) v[j] = (half_t)(w_pre[j * 64 + col] * a0);
        } else if (q == 1) {
            v[0] = (half_t)(w_pre[8 * 64 + col] * a0);
            v[1] = (half_t)c0;                      // bias channel k=9
        }
        bwp[nt] = v;

        float a1 = g_m1[col] * rsqrtf(rv_m1[col] + 1e-5f);
        sC1c[nt] = (b_m1[col] - rm_m1[col]) * a1 + be_m1[col];
        float a2 = g_m2[col] * rsqrtf(rv_m2[col] + 1e-5f);
        sC2c[nt] = (b_m2[col] - rm_m2[col]) * a2 + be_m2[col];
    }

    const int nbase = blockIdx.x * 32 + wave * 4;

    // ---- prefetch iter 0: x rows (f16, unmasked) + mask ballot ----
    half8 xraw[2];
    #pragma unroll
    for (int mt = 0; mt < 2; mt++) {
        const float* src = px + ((long)nbase * PPTS + l15 + 16 * mt) * CIN;
        half8 v = h8z();
        if (q == 0) {
            #pragma unroll
            for (int j = 0; j < 8; j++) v[j] = (half_t)src[j];
        } else if (q == 1) {
            v[0] = (half_t)src[8];
        }
        xraw[mt] = v;
    }
    unsigned mask32;
    {
        int m0 = (lane >= 32) ? pmask[nbase * PPTS + (lane - 32)] : 0;
        mask32 = (unsigned)(__ballot(m0 != 0) >> 32);   // bit r = point r of polyline
    }

    __syncthreads();   // weights staged

    for (int it = 0; it < 4; ++it) {
        const int n = nbase + it;

        // ---- issue next-iteration prefetch (consumed at iter end) ----
        half8 xnext[2]; int mnext = 0;
        if (it < 3) {
            #pragma unroll
            for (int mt = 0; mt < 2; mt++) {
                const float* src = px + ((long)(n + 1) * PPTS + l15 + 16 * mt) * CIN;
                half8 v = h8z();
                if (q == 0) {
                    #pragma unroll
                    for (int j = 0; j < 8; j++) v[j] = (half_t)src[j];
                } else if (q == 1) {
                    v[0] = (half_t)src[8];
                }
                xnext[mt] = v;
            }
            if (lane >= 32) mnext = pmask[(n + 1) * PPTS + (lane - 32)];
        }

        // ---- apply row mask to x frags + mask/bias channel ----
        half_t hm[2];
        hm[0] = (half_t)((mask32 >> l15) & 1u ? 1.f : 0.f);
        hm[1] = (half_t)((mask32 >> (l15 + 16)) & 1u ? 1.f : 0.f);
        half8 xa[2];
        #pragma unroll
        for (int mt = 0; mt < 2; mt++) {
            half8 v = xraw[mt];
            #pragma unroll
            for (int j = 0; j < 8; j++) v[j] = v[j] * hm[mt];
            if (q == 1) v[1] = hm[mt];             // k=9 mask/bias channel
            xa[mt] = v;
        }

        // ---- pre layer: f = m*relu(x@W'+sC0), acc init 0 ----
        f32x4 acc[2][4];
        #pragma unroll
        for (int mt = 0; mt < 2; mt++)
            #pragma unroll
            for (int nt = 0; nt < 4; nt++)
                #pragma unroll
                for (int r = 0; r < 4; r++) acc[mt][nt][r] = 0.f;

        #pragma unroll
        for (int nt = 0; nt < 4; nt++) {
            acc[0][nt] = MFMA(xa[0], bwp[nt], acc[0][nt]);
            acc[1][nt] = MFMA(xa[1], bwp[nt], acc[1][nt]);
        }

        // ReLU (mask already applied), write f A-tile, pooled max
        float pm[4];
        #pragma unroll
        for (int nt = 0; nt < 4; nt++) {
            float m = 0.f;
            #pragma unroll
            for (int mt = 0; mt < 2; mt++)
                #pragma unroll
                for (int r = 0; r < 4; r++) {
                    float v = fmaxf(acc[mt][nt][r], 0.f);
                    fg[wave][(mt * 16 + q * 4 + r) * FG_S + nt * 16 + l15] = (half_t)v;
                    m = fmaxf(m, v);
                }
            m = fmaxf(m, __shfl_xor(m, 16));
            m = fmaxf(m, __shfl_xor(m, 32));
            pm[nt] = m;
        }
        {
            float pv = (q == 0) ? pm[0] : (q == 1) ? pm[1] : (q == 2) ? pm[2] : pm[3];
            pooledb[wave][lane] = (half_t)pv;   // col = q*16+l15 = lane
        }

        float maskf[8];
        #pragma unroll
        for (int mt = 0; mt < 2; mt++)
            #pragma unroll
            for (int r = 0; r < 4; r++)
                maskf[mt * 4 + r] = ((mask32 >> (mt * 16 + q * 4 + r)) & 1u) ? 1.f : 0.f;

        // ---- l1: A = [f | pooled-bcast] (32x128) @ (128x64), acc init sC1 ----
        f32x4 acc1[2][4];
        #pragma unroll
        for (int mt = 0; mt < 2; mt++)
            #pragma unroll
            for (int nt = 0; nt < 4; nt++)
                #pragma unroll
                for (int r = 0; r < 4; r++) acc1[mt][nt][r] = sC1c[nt];

        half8 pa0 = ld8(&pooledb[wave][q * 8]);
        half8 pa1 = ld8(&pooledb[wave][32 + q * 8]);
        #pragma unroll
        for (int ks = 0; ks < 2; ks++) {
            half8 a0 = ld8(&fg[wave][l15 * FG_S + ks * 32 + q * 8]);
            half8 a1 = ld8(&fg[wave][(l15 + 16) * FG_S + ks * 32 + q * 8]);
            #pragma unroll
            for (int nt = 0; nt < 4; nt++) {
                half8 b = ld8(&lds_w[(ks * 4 + nt) * 512 + lane * 8]);
                acc1[0][nt] = MFMA(a0, b, acc1[0][nt]);
                acc1[1][nt] = MFMA(a1, b, acc1[1][nt]);
            }
        }
        #pragma unroll
        for (int ks = 2; ks < 4; ks++) {
            half8 ap = (ks == 2) ? pa0 : pa1;
            #pragma unroll
            for (int nt = 0; nt < 4; nt++) {
                half8 b = ld8(&lds_w[(ks * 4 + nt) * 512 + lane * 8]);
                acc1[0][nt] = MFMA(ap, b, acc1[0][nt]);
                acc1[1][nt] = MFMA(ap, b, acc1[1][nt]);
            }
        }
        // ReLU only, overwrite fg
        #pragma unroll
        for (int nt = 0; nt < 4; nt++)
            #pragma unroll
            for (int mt = 0; mt < 2; mt++)
                #pragma unroll
                for (int r = 0; r < 4; r++) {
                    float v = fmaxf(acc1[mt][nt][r], 0.f);
                    fg[wave][(mt * 16 + q * 4 + r) * FG_S + nt * 16 + l15] = (half_t)v;
                }

        // ---- l2: (32x64) @ (64x64), acc init sC2 ----
        f32x4 acc2[2][4];
        #pragma unroll
        for (int mt = 0; mt < 2; mt++)
            #pragma unroll
            for (int nt = 0; nt < 4; nt++)
                #pragma unroll
                for (int r = 0; r < 4; r++) acc2[mt][nt][r] = sC2c[nt];
        #pragma unroll
        for (int ks = 0; ks < 2; ks++) {
            half8 a0 = ld8(&fg[wave][l15 * FG_S + ks * 32 + q * 8]);
            half8 a1 = ld8(&fg[wave][(l15 + 16) * FG_S + ks * 32 + q * 8]);
            #pragma unroll
            for (int nt = 0; nt < 4; nt++) {
                half8 b = ld8(&lds_w[(16 + ks * 4 + nt) * 512 + lane * 8]);
                acc2[0][nt] = MFMA(a0, b, acc2[0][nt]);
                acc2[1][nt] = MFMA(a1, b, acc2[1][nt]);
            }
        }

        // ReLU + mask, masked max over points -> ft row
        float fm[4];
        #pragma unroll
        for (int nt = 0; nt < 4; nt++) {
            float m = 0.f;
            #pragma unroll
            for (int mt = 0; mt < 2; mt++)
                #pragma unroll
                for (int r = 0; r < 4; r++) {
                    float v = fmaxf(acc2[mt][nt][r], 0.f) * maskf[mt * 4 + r];
                    m = fmaxf(m, v);
                }
            m = fmaxf(m, __shfl_xor(m, 16));
            m = fmaxf(m, __shfl_xor(m, 32));
            fm[nt] = m;
        }
        float fv = (q == 0) ? fm[0] : (q == 1) ? fm[1] : (q == 2) ? fm[2] : fm[3];
        ft[(wave * 4 + it) * FT_S + lane] = (half_t)fv;   // local row = 4w+it, col = lane

        if (lane == 0) validb[wave * 4 + it] = (mask32 != 0u) ? 1 : 0;

        // ---- commit prefetch ----
        if (it < 3) {
            mask32 = (unsigned)(__ballot(mnext != 0) >> 32);
            xraw[0] = xnext[0];
            xraw[1] = xnext[1];
        }
    }

    // =============== out-MLP stage (M=32 rows per block) ===============
    // 8 waves <-> 8 out1 tiles (2 mrows x 4 ncols); out2: 2 tiles per wave.
    const int mt_o = wave & 1;        // row tile 0/1
    const int nt1  = wave >> 1;       // out1 col tile 0..3

    float bb1 = b1[nt1 * 16 + l15];
    half8 bw1[2];
    #pragma unroll
    for (int ks = 0; ks < 2; ks++)
        #pragma unroll
        for (int j = 0; j < 8; j++)
            bw1[ks][j] = (half_t)w1[(ks * 32 + q * 8 + j) * 64 + nt1 * 16 + l15];

    float bb2[2];
    half8 bw2[2][2];   // [ks][nn], col tile = (wave>>1)*2+nn (0..7)
    #pragma unroll
    for (int nn = 0; nn < 2; nn++) {
        int c = ((wave >> 1) * 2 + nn) * 16 + l15;
        bb2[nn] = b2[c];
        #pragma unroll
        for (int ks = 0; ks < 2; ks++)
            #pragma unroll
            for (int j = 0; j < 8; j++)
                bw2[ks][nn][j] = (half_t)w2[(ks * 32 + q * 8 + j) * 128 + c];
    }

    __syncthreads();   // ft + validb complete

    // out1: tile (mt_o, nt1)
    f32x4 o1;
    #pragma unroll
    for (int r = 0; r < 4; r++) o1[r] = bb1;
    #pragma unroll
    for (int ks = 0; ks < 2; ks++) {
        half8 a = ld8(&ft[(mt_o * 16 + l15) * FT_S + ks * 32 + q * 8]);
        o1 = MFMA(a, bw1[ks], o1);
    }
    #pragma unroll
    for (int r = 0; r < 4; r++) {
        float v = fmaxf(o1[r], 0.f);
        qt[(mt_o * 16 + q * 4 + r) * FT_S + nt1 * 16 + l15] = (half_t)v;
    }

    __syncthreads();   // qt complete

    // out2: tiles (mt_o, 2*(wave>>1)+nn)
    f32x4 o2[2];
    #pragma unroll
    for (int nn = 0; nn < 2; nn++)
        #pragma unroll
        for (int r = 0; r < 4; r++) o2[nn][r] = bb2[nn];
    #pragma unroll
    for (int ks = 0; ks < 2; ks++) {
        half8 a = ld8(&qt[(mt_o * 16 + l15) * FT_S + ks * 32 + q * 8]);
        o2[0] = MFMA(a, bw2[ks][0], o2[0]);
        o2[1] = MFMA(a, bw2[ks][1], o2[1]);
    }
    #pragma unroll
    for (int r = 0; r < 4; r++) {
        int lrow = mt_o * 16 + q * 4 + r;
        float vr = validb[lrow] ? 1.f : 0.f;
        long rowg = (long)(blockIdx.x * 32 + lrow);
        out[rowg * 128 + ((wave >> 1) * 2 + 0) * 16 + l15] = o2[0][r] * vr;
        out[rowg * 128 + ((wave >> 1) * 2 + 1) * 16 + l15] = o2[1][r] * vr;
    }
}

extern "C" void kernel_launch(void* const* d_in, const int* in_sizes, int n_in,
                              void* d_out, int out_size, void* d_ws, size_t ws_size,
                              hipStream_t stream) {
    (void)in_sizes; (void)n_in; (void)out_size; (void)d_ws; (void)ws_size;
    k_fused<<<dim3(NPOLY / 32), dim3(512), 0, stream>>>(
        (const float*)d_in[0], (const int*)d_in[1],
        (const float*)d_in[2],  (const float*)d_in[3],  (const float*)d_in[4],
        (const float*)d_in[5],  (const float*)d_in[6],  (const float*)d_in[7],
        (const float*)d_in[8],  (const float*)d_in[9],  (const float*)d_in[10],
        (const float*)d_in[11], (const float*)d_in[12], (const float*)d_in[13],
        (const float*)d_in[14], (const float*)d_in[15], (const float*)d_in[16],
        (const float*)d_in[17], (const float*)d_in[18], (const float*)d_in[19],
        (const float*)d_in[20], (const float*)d_in[21],
        (const float*)d_in[22], (const float*)d_in[23],
        (float*)d_out);
}

// Round 7
// 152.092 us; speedup vs baseline: 1.0690x; 1.0690x over previous
//
#include <hip/hip_runtime.h>

typedef _Float16 half_t;
typedef __attribute__((ext_vector_type(8))) _Float16 half8;   // MFMA A/B frag (4 VGPRs)
typedef __attribute__((ext_vector_type(4))) float f32x4;      // MFMA C/D frag

#define NPOLY 16384   // B*N
#define PPTS  32
#define CIN   9
#define FG_S  68      // fg row stride (halves): write banks 2-way max (free, m136)
#define FT_S  72      // ft/qt row stride
#define NFRAG 52      // ws frag count: pre 0..3, m1 4..19, m2 20..27, w1 28..35, w2 36..51
#define FLOATS_OFF (NFRAG * 512)   // halves; f32 region: sC1[64], sC2[64], b1[64], b2[128]

__device__ __forceinline__ half8 ld8(const half_t* p){
    return *reinterpret_cast<const half8*>(p);
}
__device__ __forceinline__ half8 h8z(){
    half8 v;
    #pragma unroll
    for (int j = 0; j < 8; j++) v[j] = (half_t)0.f;
    return v;
}
__device__ __forceinline__ f32x4 MFMA(half8 a, half8 b, f32x4 c){
    return __builtin_amdgcn_mfma_f32_16x16x32_f16(a, b, c, 0, 0, 0);
}
// Fragment layouts (measured, learn_hip m89/m120; dtype-independent):
//   A[m][k]: m = lane&15 (+16*mt), k = (lane>>4)*8 + j (+32*ks)
//   B[k][n]: n = lane&15 (+16*nt), k = (lane>>4)*8 + j (+32*ks)
//   C/D[row][col]: col = lane&15 (+16*nt), row = (lane>>4)*4 + r (+16*mt)

// =====================================================================
// k_prep: convert all weights to f16 B-frags in ws (BN scale folded,
// pre-layer bias as mask-channel row k=9), plus f32 consts region.
// 13 blocks x 256 = 3328 threads = 52 frags x 64 lanes.
// =====================================================================
__global__ void k_prep(
    const float* __restrict__ w_pre, const float* __restrict__ b_pre,
    const float* __restrict__ g_pre, const float* __restrict__ be_pre,
    const float* __restrict__ rm_pre, const float* __restrict__ rv_pre,
    const float* __restrict__ w_m1, const float* __restrict__ b_m1,
    const float* __restrict__ g_m1, const float* __restrict__ be_m1,
    const float* __restrict__ rm_m1, const float* __restrict__ rv_m1,
    const float* __restrict__ w_m2, const float* __restrict__ b_m2,
    const float* __restrict__ g_m2, const float* __restrict__ be_m2,
    const float* __restrict__ rm_m2, const float* __restrict__ rv_m2,
    const float* __restrict__ w1, const float* __restrict__ b1,
    const float* __restrict__ w2, const float* __restrict__ b2,
    half_t* __restrict__ ws_h)
{
    const int s = blockIdx.x * 256 + threadIdx.x;
    const int frag = s >> 6, ln = s & 63;
    const int l15 = ln & 15, qq = ln >> 4;
    half8 v = h8z();

    if (frag < 4) {                       // pre: nt=frag, K=9 + bias channel k=9
        int col = frag * 16 + l15;
        float a0 = g_pre[col] * rsqrtf(rv_pre[col] + 1e-5f);
        float c0 = (b_pre[col] - rm_pre[col]) * a0 + be_pre[col];
        if (qq == 0) {
            #pragma unroll
            for (int j = 0; j < 8; j++) v[j] = (half_t)(w_pre[j * 64 + col] * a0);
        } else if (qq == 1) {
            v[0] = (half_t)(w_pre[8 * 64 + col] * a0);
            v[1] = (half_t)c0;
        }
    } else if (frag < 20) {               // m1: ks=(f-4)>>2, nt=(f-4)&3, K=128
        int f = frag - 4, ks = f >> 2, nt = f & 3;
        int col = nt * 16 + l15;
        float a1 = g_m1[col] * rsqrtf(rv_m1[col] + 1e-5f);
        #pragma unroll
        for (int j = 0; j < 8; j++)
            v[j] = (half_t)(w_m1[(ks * 32 + qq * 8 + j) * 64 + col] * a1);
    } else if (frag < 28) {               // m2: ks=(f-20)>>2, nt, K=64
        int f = frag - 20, ks = f >> 2, nt = f & 3;
        int col = nt * 16 + l15;
        float a2 = g_m2[col] * rsqrtf(rv_m2[col] + 1e-5f);
        #pragma unroll
        for (int j = 0; j < 8; j++)
            v[j] = (half_t)(w_m2[(ks * 32 + qq * 8 + j) * 64 + col] * a2);
    } else if (frag < 36) {               // w1: ks=(f-28)>>2, nt
        int f = frag - 28, ks = f >> 2, nt = f & 3;
        #pragma unroll
        for (int j = 0; j < 8; j++)
            v[j] = (half_t)(w1[(ks * 32 + qq * 8 + j) * 64 + nt * 16 + l15]);
    } else {                              // w2: ks=(f-36)>>3, ct=(f-36)&7
        int f = frag - 36, ks = f >> 3, ct = f & 7;
        #pragma unroll
        for (int j = 0; j < 8; j++)
            v[j] = (half_t)(w2[(ks * 32 + qq * 8 + j) * 128 + ct * 16 + l15]);
    }
    *reinterpret_cast<half8*>(ws_h + (long)frag * 512 + ln * 8) = v;

    if (blockIdx.x == 12) {               // f32 consts region
        float* F = reinterpret_cast<float*>(ws_h + FLOATS_OFF);
        int t = threadIdx.x;
        if (t < 64) {
            float a1 = g_m1[t] * rsqrtf(rv_m1[t] + 1e-5f);
            F[t] = (b_m1[t] - rm_m1[t]) * a1 + be_m1[t];
            F[256 + t] = b2[64 + t];
        } else if (t < 128) {
            int c = t - 64;
            float a2 = g_m2[c] * rsqrtf(rv_m2[c] + 1e-5f);
            F[64 + c] = (b_m2[c] - rm_m2[c]) * a2 + be_m2[c];
        } else if (t < 192) {
            F[128 + (t - 128)] = b1[t - 128];
        } else {
            F[192 + (t - 192)] = b2[t - 192];
        }
    }
}

// =====================================================================
// k_fused: fully fused encoder + out-MLPs.
// 1024 blocks x 256 threads (4 waves) = 16 polylines/block; wave owns 4.
// All weight frags stream from ws (L1-resident, 26 KB); LDS ~23 KB ->
// residency limited only by regs: __launch_bounds__(256,4) caps
// VGPR+AGPR total at 128 -> 4 waves/SIMD -> all 4 blocks/CU co-resident
// (entire grid resident in one round, no tail). No barrier until the
// out-stage join.
// =====================================================================
__global__ __launch_bounds__(256, 4) void k_fused(
    const float* __restrict__ px,        // [NPOLY][32][9]
    const int*   __restrict__ pmask,     // [NPOLY][32]
    const half_t* __restrict__ ws_h,
    float* __restrict__ out)
{
    __shared__ __align__(16) half_t fg[4][32 * FG_S];    // 17 KB per-wave f/g A-tiles
    __shared__ __align__(16) half_t pooledb[4][64];      // 0.5 KB
    __shared__ __align__(16) half_t ft[16 * FT_S];       // 2.25 KB feat A-tile
    __shared__ __align__(16) half_t qt[16 * FT_S];       // 2.25 KB out1 A-tile
    __shared__ int validb[16];

    const int tid  = threadIdx.x;
    const int wave = tid >> 6, lane = tid & 63, l15 = lane & 15, q = lane >> 4;
    const float* F = reinterpret_cast<const float*>(ws_h + FLOATS_OFF);

    float sC1c[4], sC2c[4];
    #pragma unroll
    for (int nt = 0; nt < 4; nt++) {
        sC1c[nt] = F[nt * 16 + l15];
        sC2c[nt] = F[64 + nt * 16 + l15];
    }

    const int nbase = blockIdx.x * 16 + wave * 4;

    // ---- prefetch iter 0: x rows (f16, unmasked) + mask ballot ----
    half8 xraw[2];
    #pragma unroll
    for (int mt = 0; mt < 2; mt++) {
        const float* src = px + ((long)nbase * PPTS + l15 + 16 * mt) * CIN;
        half8 v = h8z();
        if (q == 0) {
            #pragma unroll
            for (int j = 0; j < 8; j++) v[j] = (half_t)src[j];
        } else if (q == 1) {
            v[0] = (half_t)src[8];
        }
        xraw[mt] = v;
    }
    unsigned mask32;
    {
        int m0 = (lane >= 32) ? pmask[nbase * PPTS + (lane - 32)] : 0;
        mask32 = (unsigned)(__ballot(m0 != 0) >> 32);
    }

    for (int it = 0; it < 4; ++it) {
        const int n = nbase + it;

        // launder ws base: blocks LICM/CSE from hoisting 28 frag loads
        // (112 regs) out of the loop — the R4 spill disaster, compiler-made.
        const half_t* wsl;
        {
            unsigned long long p = (unsigned long long)ws_h;
            asm volatile("" : "+s"(p));
            wsl = (const half_t*)p;
        }

        // ---- issue next-iteration prefetch ----
        half8 xnext[2]; int mnext = 0;
        if (it < 3) {
            #pragma unroll
            for (int mt = 0; mt < 2; mt++) {
                const float* src = px + ((long)(n + 1) * PPTS + l15 + 16 * mt) * CIN;
                half8 v = h8z();
                if (q == 0) {
                    #pragma unroll
                    for (int j = 0; j < 8; j++) v[j] = (half_t)src[j];
                } else if (q == 1) {
                    v[0] = (half_t)src[8];
                }
                xnext[mt] = v;
            }
            if (lane >= 32) mnext = pmask[(n + 1) * PPTS + (lane - 32)];
        }

        // ---- apply row mask in place + mask/bias channel ----
        half_t hm[2];
        hm[0] = (half_t)((mask32 >> l15) & 1u ? 1.f : 0.f);
        hm[1] = (half_t)((mask32 >> (l15 + 16)) & 1u ? 1.f : 0.f);
        #pragma unroll
        for (int mt = 0; mt < 2; mt++) {
            #pragma unroll
            for (int j = 0; j < 8; j++) xraw[mt][j] = xraw[mt][j] * hm[mt];
            if (q == 1) xraw[mt][1] = hm[mt];      // k=9 mask/bias channel
        }

        f32x4 acc[2][4];   // single acc set reused by all three layers (AGPR budget)

        // ---- pre layer: f = m*relu(x@W'+sC0) ----
        #pragma unroll
        for (int mt = 0; mt < 2; mt++)
            #pragma unroll
            for (int nt = 0; nt < 4; nt++)
                #pragma unroll
                for (int r = 0; r < 4; r++) acc[mt][nt][r] = 0.f;
        #pragma unroll
        for (int nt = 0; nt < 4; nt++) {
            half8 b = ld8(wsl + nt * 512 + lane * 8);
            acc[0][nt] = MFMA(xraw[0], b, acc[0][nt]);
            acc[1][nt] = MFMA(xraw[1], b, acc[1][nt]);
        }

        // ReLU (mask already in), write f A-tile, pooled max
        float pm[4];
        #pragma unroll
        for (int nt = 0; nt < 4; nt++) {
            float m = 0.f;
            #pragma unroll
            for (int mt = 0; mt < 2; mt++)
                #pragma unroll
                for (int r = 0; r < 4; r++) {
                    float v = fmaxf(acc[mt][nt][r], 0.f);
                    fg[wave][(mt * 16 + q * 4 + r) * FG_S + nt * 16 + l15] = (half_t)v;
                    m = fmaxf(m, v);
                }
            m = fmaxf(m, __shfl_xor(m, 16));
            m = fmaxf(m, __shfl_xor(m, 32));
            pm[nt] = m;
        }
        {
            float pv = (q == 0) ? pm[0] : (q == 1) ? pm[1] : (q == 2) ? pm[2] : pm[3];
            pooledb[wave][lane] = (half_t)pv;   // col = lane
        }

        // ---- l1: A = [f | pooled-bcast] (32x128) @ (128x64) ----
        #pragma unroll
        for (int mt = 0; mt < 2; mt++)
            #pragma unroll
            for (int nt = 0; nt < 4; nt++)
                #pragma unroll
                for (int r = 0; r < 4; r++) acc[mt][nt][r] = sC1c[nt];

        half8 pa0 = ld8(&pooledb[wave][q * 8]);
        half8 pa1 = ld8(&pooledb[wave][32 + q * 8]);
        #pragma unroll
        for (int ks = 0; ks < 2; ks++) {
            half8 a0 = ld8(&fg[wave][l15 * FG_S + ks * 32 + q * 8]);
            half8 a1 = ld8(&fg[wave][(l15 + 16) * FG_S + ks * 32 + q * 8]);
            #pragma unroll
            for (int nt = 0; nt < 4; nt++) {
                half8 b = ld8(wsl + (4 + ks * 4 + nt) * 512 + lane * 8);
                acc[0][nt] = MFMA(a0, b, acc[0][nt]);
                acc[1][nt] = MFMA(a1, b, acc[1][nt]);
            }
        }
        #pragma unroll
        for (int ks = 2; ks < 4; ks++) {
            half8 ap = (ks == 2) ? pa0 : pa1;
            #pragma unroll
            for (int nt = 0; nt < 4; nt++) {
                half8 b = ld8(wsl + (4 + ks * 4 + nt) * 512 + lane * 8);
                acc[0][nt] = MFMA(ap, b, acc[0][nt]);
                acc[1][nt] = MFMA(ap, b, acc[1][nt]);
            }
        }
        // ReLU only, overwrite fg
        #pragma unroll
        for (int nt = 0; nt < 4; nt++)
            #pragma unroll
            for (int mt = 0; mt < 2; mt++)
                #pragma unroll
                for (int r = 0; r < 4; r++) {
                    float v = fmaxf(acc[mt][nt][r], 0.f);
                    fg[wave][(mt * 16 + q * 4 + r) * FG_S + nt * 16 + l15] = (half_t)v;
                }

        // ---- l2: (32x64) @ (64x64), then masked max -> ft ----
        float s2[2][4][4];
        #pragma unroll
        for (int mt = 0; mt < 2; mt++)
            #pragma unroll
            for (int nt = 0; nt < 4; nt++)
                #pragma unroll
                for (int r = 0; r < 4; r++) acc[mt][nt][r] = sC2c[nt];
        #pragma unroll
        for (int ks = 0; ks < 2; ks++) {
            half8 a0 = ld8(&fg[wave][l15 * FG_S + ks * 32 + q * 8]);
            half8 a1 = ld8(&fg[wave][(l15 + 16) * FG_S + ks * 32 + q * 8]);
            #pragma unroll
            for (int nt = 0; nt < 4; nt++) {
                half8 b = ld8(wsl + (20 + ks * 4 + nt) * 512 + lane * 8);
                acc[0][nt] = MFMA(a0, b, acc[0][nt]);
                acc[1][nt] = MFMA(a1, b, acc[1][nt]);
            }
        }
        #pragma unroll
        for (int mt = 0; mt < 2; mt++)
            #pragma unroll
            for (int nt = 0; nt < 4; nt++)
                #pragma unroll
                for (int r = 0; r < 4; r++) s2[mt][nt][r] = acc[mt][nt][r];

        float fm[4];
        #pragma unroll
        for (int nt = 0; nt < 4; nt++) {
            float m = 0.f;
            #pragma unroll
            for (int mt = 0; mt < 2; mt++)
                #pragma unroll
                for (int r = 0; r < 4; r++) {
                    float mk = ((mask32 >> (mt * 16 + q * 4 + r)) & 1u) ? 1.f : 0.f;
                    m = fmaxf(m, fmaxf(s2[mt][nt][r], 0.f) * mk);
                }
            m = fmaxf(m, __shfl_xor(m, 16));
            m = fmaxf(m, __shfl_xor(m, 32));
            fm[nt] = m;
        }
        float fv = (q == 0) ? fm[0] : (q == 1) ? fm[1] : (q == 2) ? fm[2] : fm[3];
        ft[(wave * 4 + it) * FT_S + lane] = (half_t)fv;

        if (lane == 0) validb[wave * 4 + it] = (mask32 != 0u) ? 1 : 0;

        // ---- commit prefetch ----
        if (it < 3) {
            mask32 = (unsigned)(__ballot(mnext != 0) >> 32);
            xraw[0] = xnext[0];
            xraw[1] = xnext[1];
        }
    }

    // =============== out-MLP stage (M=16 rows per block) ===============
    float bb1 = F[128 + wave * 16 + l15];
    half8 bw1[2];
    #pragma unroll
    for (int ks = 0; ks < 2; ks++)
        bw1[ks] = ld8(ws_h + (28 + ks * 4 + wave) * 512 + lane * 8);

    float bb2[2];
    half8 bw2[2][2];
    #pragma unroll
    for (int nn = 0; nn < 2; nn++) {
        int c = wave * 2 + nn;
        bb2[nn] = F[192 + c * 16 + l15];
        #pragma unroll
        for (int ks = 0; ks < 2; ks++)
            bw2[ks][nn] = ld8(ws_h + (36 + ks * 8 + c) * 512 + lane * 8);
    }

    __syncthreads();   // ft + validb complete

    // out1: wave w computes cols w*16..w*16+15
    f32x4 o1;
    #pragma unroll
    for (int r = 0; r < 4; r++) o1[r] = bb1;
    #pragma unroll
    for (int ks = 0; ks < 2; ks++) {
        half8 a = ld8(&ft[l15 * FT_S + ks * 32 + q * 8]);
        o1 = MFMA(a, bw1[ks], o1);
    }
    #pragma unroll
    for (int r = 0; r < 4; r++) {
        float v = fmaxf(o1[r], 0.f);
        qt[(q * 4 + r) * FT_S + wave * 16 + l15] = (half_t)v;
    }

    __syncthreads();   // qt complete

    // out2: wave w computes cols (2w)*16 .. (2w+1)*16+15
    f32x4 o2[2];
    #pragma unroll
    for (int nn = 0; nn < 2; nn++)
        #pragma unroll
        for (int r = 0; r < 4; r++) o2[nn][r] = bb2[nn];
    #pragma unroll
    for (int ks = 0; ks < 2; ks++) {
        half8 a = ld8(&qt[l15 * FT_S + ks * 32 + q * 8]);
        o2[0] = MFMA(a, bw2[ks][0], o2[0]);
        o2[1] = MFMA(a, bw2[ks][1], o2[1]);
    }
    #pragma unroll
    for (int r = 0; r < 4; r++) {
        float vr = validb[q * 4 + r] ? 1.f : 0.f;
        long rowg = (long)(blockIdx.x * 16 + q * 4 + r);
        out[rowg * 128 + (wave * 2 + 0) * 16 + l15] = o2[0][r] * vr;
        out[rowg * 128 + (wave * 2 + 1) * 16 + l15] = o2[1][r] * vr;
    }
}

extern "C" void kernel_launch(void* const* d_in, const int* in_sizes, int n_in,
                              void* d_out, int out_size, void* d_ws, size_t ws_size,
                              hipStream_t stream) {
    (void)in_sizes; (void)n_in; (void)out_size; (void)ws_size;
    half_t* ws_h = (half_t*)d_ws;

    k_prep<<<dim3(13), dim3(256), 0, stream>>>(
        (const float*)d_in[2],  (const float*)d_in[3],  (const float*)d_in[4],
        (const float*)d_in[5],  (const float*)d_in[6],  (const float*)d_in[7],
        (const float*)d_in[8],  (const float*)d_in[9],  (const float*)d_in[10],
        (const float*)d_in[11], (const float*)d_in[12], (const float*)d_in[13],
        (const float*)d_in[14], (const float*)d_in[15], (const float*)d_in[16],
        (const float*)d_in[17], (const float*)d_in[18], (const float*)d_in[19],
        (const float*)d_in[20], (const float*)d_in[21],
        (const float*)d_in[22], (const float*)d_in[23],
        ws_h);

    k_fused<<<dim3(NPOLY / 16), dim3(256), 0, stream>>>(
        (const float*)d_in[0], (const int*)d_in[1], ws_h, (float*)d_out);
}